// Round 2
// baseline (13754.216 us; speedup 1.0000x reference)
//
#include <hip/hip_runtime.h>
#include <cstdint>

#define B_  128
#define T_  1024
#define DIN 13
#define HS  256
#define N0  77
#define N1  51
#define N2  128

// gates: K = 13 (x) + 1 (pad) + 256 (h) = 270 -> padded pairs K2G = 136
#define K2G 136
#define QG  34
#define NRG 1024

#define K0   90
#define K2_0 48
#define Q0   12
#define NR0  308

#define K1   128
#define K2_1 64
#define Q1   16
#define NR1  204

#define KL2  179
#define K2_2 96
#define Q2   24
#define NR2  512

// new pair-split l2 packing: K pad 179 -> 184 (92 pairs, 23 quads)
#define K2N  92
#define Q2N  23
#define UA   28          // A's l2 units (0..27)
#define UB   100         // B's l2 units (28..127)
#define RA   (4*UA)      // 112 rows
#define RB   (4*UB)      // 400 rows

typedef _Float16 h2_t __attribute__((ext_vector_type(2)));

static __device__ __forceinline__ uint32_t pk2(float a, float b) {
  h2_t v; v.x = (_Float16)a; v.y = (_Float16)b;
  return __builtin_bit_cast(uint32_t, v);
}
static __device__ __forceinline__ float dot2f(uint32_t w, uint32_t z, float acc) {
#if __has_builtin(__builtin_amdgcn_fdot2)
  return __builtin_amdgcn_fdot2(__builtin_bit_cast(h2_t, w), __builtin_bit_cast(h2_t, z), acc, false);
#else
  h2_t a = __builtin_bit_cast(h2_t, w), b = __builtin_bit_cast(h2_t, z);
  return acc + (float)a.x * (float)b.x + (float)a.y * (float)b.y;
#endif
}
static __device__ __forceinline__ float dot8f(uint4 w, uint4 z, float acc) {
  acc = dot2f(w.x, z.x, acc);
  acc = dot2f(w.y, z.y, acc);
  acc = dot2f(w.z, z.z, acc);
  acc = dot2f(w.w, z.w, acc);
  return acc;
}
static __device__ __forceinline__ float sigf(float x) { return 1.f / (1.f + expf(-x)); }

// ---------------- prep kernels: f32 -> packed f16, transposed quad-interleaved ----------------

__global__ void prep_gates(const float* __restrict__ Wih, const float* __restrict__ Whh,
                           uint32_t* __restrict__ out) {
  int id = blockIdx.x * blockDim.x + threadIdx.x;
  if (id >= K2G * NRG) return;
  int k2 = id >> 10, row = id & (NRG - 1);
  float v[2];
#pragma unroll
  for (int j = 0; j < 2; ++j) {
    int k = 2 * k2 + j;
    float val = 0.f;
    if (k < DIN) val = Wih[row * DIN + k];
    else if (k >= 14 && k < 14 + HS) val = Whh[row * HS + (k - 14)];
    v[j] = val;
  }
  out[((k2 >> 2) * NRG + row) * 4 + (k2 & 3)] = pk2(v[0], v[1]);
}

__global__ void prep_cfc(const float* __restrict__ Wf1, const float* __restrict__ Wf2,
                         const float* __restrict__ Wta, const float* __restrict__ Wtb,
                         const float* __restrict__ mask,
                         int nh, int nin, int NR, int K2pad, uint32_t* __restrict__ out) {
  int id = blockIdx.x * blockDim.x + threadIdx.x;
  if (id >= NR * K2pad) return;
  int k2 = id / NR, r = id % NR;
  int mat = r / nh, o = r % nh;
  const float* W = (mat == 0) ? Wf1 : (mat == 1) ? Wf2 : (mat == 2) ? Wta : Wtb;
  int K = nin + nh;
  float v[2];
#pragma unroll
  for (int j = 0; j < 2; ++j) {
    int k = 2 * k2 + j;
    float val = 0.f;
    if (k < K) {
      val = W[o * K + k];
      if (mat < 2) val *= mask[o * K + k];
    }
    v[j] = val;
  }
  out[((k2 >> 2) * NR + r) * 4 + (k2 & 3)] = pk2(v[0], v[1]);
}

// ================= pair-split persistent kernel (new path) =================

struct SMA {
  uint4 l0w[Q0 * NR0];
  uint4 l1w[Q1 * NR1];
  uint4 l2w[Q2N * RA];
  uint4 zg[QG];
  uint4 z0[Q0];
  uint4 z1[Q1];
  uint4 z2[Q2N];
  float xt[16];
  float hA[128];        // lstm h[0:128]
  float garr[512];
  float ffb[4][80];
  float l0o[80];
  float l1o[64];
  float l2o[32];
  float h2[128];        // lstm h[128:256] (recv)
  float cb0[NR0];
  float cb1[NR1];
  float cb2[RA];
};
struct SMB {
  uint4 l2w[Q2N * RB];
  uint4 zg[QG];
  uint4 z2[Q2N];
  float xt[16];
  float hB[128];        // lstm h[128:256]
  float garr[512];
  float motor[128];
  float cb2[RB];
  float hw[12][132];
  float hb[12];
  float part[12][4];
};
static_assert(sizeof(SMA) <= 163840, "SMA too big");
static_assert(sizeof(SMB) <= 163840, "SMB too big");

struct PArgs {
  const float* x;
  const float* bih; const float* bhh;
  const float* b0[4]; const float* b1[4]; const float* b2[4];
  const float* gW; const float* gb; const float* aW; const float* ab;
  const float* uW; const float* ub;
  const uint4* wsG; const uint4* wsL0; const uint4* wsL1; const uint4* wsL2;
  float* S1; float* S2; float* S3a; float* S3b; int* flags;
  float* out;
};

__global__ __launch_bounds__(512, 1) void rnn_pair(PArgs P) {
  extern __shared__ char smraw[];
  const int tid = threadIdx.x;
  const bool isA = (blockIdx.x < B_);
  const int b = blockIdx.x & (B_ - 1);
  const float* xb = P.x + (size_t)b * T_ * DIN;
  int* f1  = P.flags + b * 32 + 0;
  int* f2  = P.flags + b * 32 + 8;
  int* f3a = P.flags + b * 32 + 16;
  int* f3b = P.flags + b * 32 + 24;
  float* S1  = P.S1 + b * 128;
  float* S2  = P.S2 + b * 128;
  float* S3a = P.S3a + b * 32;
  float* S3b = P.S3b + b * 128;
  const size_t UNC_OFF = (size_t)B_ * T_ * 6;

  if (isA) {
    SMA& sm = *(SMA*)smraw;
    for (int i = tid; i < Q0 * NR0; i += 512) sm.l0w[i] = P.wsL0[i];
    for (int i = tid; i < Q1 * NR1; i += 512) sm.l1w[i] = P.wsL1[i];
    for (int i = tid; i < Q2N * RA; i += 512) {
      int q = i / RA, r = i % RA, mat = r / UA, u = r % UA;
      sm.l2w[i] = P.wsL2[q * NR2 + mat * 128 + u];
    }
    for (int i = tid; i < NR0; i += 512) sm.cb0[i] = P.b0[i / N0][i % N0];
    for (int i = tid; i < NR1; i += 512) sm.cb1[i] = P.b1[i / N1][i % N1];
    for (int i = tid; i < RA; i += 512) sm.cb2[i] = P.b2[i / UA][i % UA];
    {
      uint32_t* z = (uint32_t*)sm.zg;
      for (int i = tid; i < (QG + Q0 + Q1 + Q2N) * 4; i += 512) z[i] = 0u;
    }
    if (tid < 16) sm.xt[tid] = (tid < DIN) ? xb[tid] : 0.f;
    const int grow = ((tid >> 7) << 8) + (tid & 127);   // g*256 + u, units 0..127
    const float bg = P.bih[grow] + P.bhh[grow];
    float c_r = 0.f;
    __syncthreads();
    if (tid < 7) {
      float a0 = xb[2 * tid];
      float a1 = (tid == 6) ? 0.f : xb[2 * tid + 1];
      ((uint32_t*)sm.zg)[tid] = pk2(a0, a1);
    }
    __syncthreads();

    for (int t = 0; t < T_; ++t) {
      // P1: gates (stream this WG's 512 rows from L2)
      {
        float acc = bg;
#pragma unroll 8
        for (int q = 0; q < QG; ++q)
          acc = dot8f(P.wsG[q * NRG + grow], sm.zg[q], acc);
        sm.garr[tid] = acc;
      }
      __syncthreads();
      // P2: LSTM units 0..127
      if (tid < 128) {
        float gi = sm.garr[tid], gf = sm.garr[128 + tid];
        float gg = sm.garr[256 + tid], go = sm.garr[384 + tid];
        float cn = sigf(gf) * c_r + sigf(gi) * tanhf(gg);
        c_r = cn;
        sm.hA[tid] = sigf(go) * tanhf(cn);
      }
      __syncthreads();
      // P3: z0 pack (45 words) + z1 hi words (39..63, pure lstm region)
      if (tid < 45) {
        int k = 2 * tid;
        float a0 = (k < DIN) ? sm.xt[k] : sm.hA[k - DIN];
        ++k;
        float a1 = (k < DIN) ? sm.xt[k] : sm.hA[k - DIN];
        ((uint32_t*)sm.z0)[tid] = pk2(a0, a1);
      } else if (tid >= 64 && tid < 89) {
        int j = 39 + (tid - 64);
        ((uint32_t*)sm.z1)[j] = pk2(sm.hA[2 * j], sm.hA[2 * j + 1]);
      }
      __syncthreads();
      // P4: l0 matvec
      if (tid < NR0) {
        float a = sm.cb0[tid];
#pragma unroll
        for (int q = 0; q < Q0; ++q) a = dot8f(sm.l0w[q * NR0 + tid], sm.z0[q], a);
        int mat = tid / N0, o = tid - mat * N0;
        sm.ffb[mat][o] = (mat < 2) ? tanhf(a) : a;
      }
      __syncthreads();
      // P5: combine l0
      if (tid < N0) {
        float ti = sigf(sm.ffb[2][tid] + sm.ffb[3][tid]);
        sm.l0o[tid] = sm.ffb[0][tid] * (1.f - ti) + ti * sm.ffb[1][tid];
      }
      __syncthreads();
      // P6: z1 lo words 0..38
      if (tid < 39) {
        int k = 2 * tid;
        float a0 = sm.l0o[k];
        float a1 = (k + 1 < N0) ? sm.l0o[k + 1] : sm.hA[77];
        ((uint32_t*)sm.z1)[tid] = pk2(a0, a1);
      }
      __syncthreads();
      // P7: l1 matvec
      if (tid < NR1) {
        float a = sm.cb1[tid];
#pragma unroll
        for (int q = 0; q < Q1; ++q) a = dot8f(sm.l1w[q * NR1 + tid], sm.z1[q], a);
        int mat = tid / N1, o = tid - mat * N1;
        sm.ffb[mat][o] = (mat < 2) ? tanhf(a) : a;
      }
      __syncthreads();
      // P8: combine l1
      if (tid < N1) {
        float ti = sigf(sm.ffb[2][tid] + sm.ffb[3][tid]);
        sm.l1o[tid] = sm.ffb[0][tid] * (1.f - ti) + ti * sm.ffb[1][tid];
      }
      __syncthreads();
      // P9: S2 store (h[0:128]) + zg h-words 0..63
      if (tid < 128) {
        S2[tid] = (tid < N0) ? sm.l0o[tid] : sm.l1o[tid - N0];
      } else if (tid < 192) {
        int j = tid - 128;
        int k = 2 * j;
        float a0 = (k < N0) ? sm.l0o[k] : sm.l1o[k - N0];
        float a1 = (k + 1 < N0) ? sm.l0o[k + 1] : sm.l1o[k + 1 - N0];
        ((uint32_t*)sm.zg)[7 + j] = pk2(a0, a1);
      }
      __syncthreads();
      // P10: release f2, wait f1
      if (tid == 0) {
        __hip_atomic_store(f2, t + 1, __ATOMIC_RELEASE, __HIP_MEMORY_SCOPE_AGENT);
        while (__hip_atomic_load(f1, __ATOMIC_RELAXED, __HIP_MEMORY_SCOPE_AGENT) < t + 1)
          __builtin_amdgcn_s_sleep(1);
        (void)__hip_atomic_load(f1, __ATOMIC_ACQUIRE, __HIP_MEMORY_SCOPE_AGENT);
      }
      __syncthreads();
      // P11: copy S1 -> h2
      if (tid < 128) sm.h2[tid] = S1[tid];
      __syncthreads();
      // P12: z2 pack (92 words)
      if (tid < K2N) {
        int k = 2 * tid;
        float a0 = (k < N1) ? sm.l1o[k] : ((k < KL2) ? sm.h2[k - N1] : 0.f);
        ++k;
        float a1 = (k < N1) ? sm.l1o[k] : ((k < KL2) ? sm.h2[k - N1] : 0.f);
        ((uint32_t*)sm.z2)[tid] = pk2(a0, a1);
      }
      __syncthreads();
      // P13: l2A rows (112 threads)
      if (tid < RA) {
        float a = sm.cb2[tid];
#pragma unroll
        for (int q = 0; q < Q2N; ++q) a = dot8f(sm.l2w[q * RA + tid], sm.z2[q], a);
        int mat = tid / UA, u = tid - mat * UA;
        sm.ffb[mat][u] = (mat < 2) ? tanhf(a) : a;
      }
      __syncthreads();
      // P13b: combine l2A + S3a store
      if (tid < UA) {
        float ti = sigf(sm.ffb[2][tid] + sm.ffb[3][tid]);
        float v = sm.ffb[0][tid] * (1.f - ti) + ti * sm.ffb[1][tid];
        sm.l2o[tid] = v;
        S3a[tid] = v;
      }
      __syncthreads();
      // P14: release f3a, wait f3b
      if (tid == 0) {
        __hip_atomic_store(f3a, t + 1, __ATOMIC_RELEASE, __HIP_MEMORY_SCOPE_AGENT);
        while (__hip_atomic_load(f3b, __ATOMIC_RELAXED, __HIP_MEMORY_SCOPE_AGENT) < t + 1)
          __builtin_amdgcn_s_sleep(1);
        (void)__hip_atomic_load(f3b, __ATOMIC_ACQUIRE, __HIP_MEMORY_SCOPE_AGENT);
      }
      __syncthreads();
      // P15: tail — zg h-words 64..127 + next x
      if (tid < 14) {
        ((uint32_t*)sm.zg)[7 + 64 + tid] = pk2(sm.l2o[2 * tid], sm.l2o[2 * tid + 1]);
      } else if (tid >= 16 && tid < 66) {
        int j = 78 + (tid - 16);
        ((uint32_t*)sm.zg)[7 + j] = pk2(S3b[2 * j - 156], S3b[2 * j - 155]);
      } else if (tid >= 80 && tid < 96) {
        if (t + 1 < T_) {
          int i = tid - 80;
          sm.xt[i] = (i < DIN) ? xb[(size_t)(t + 1) * DIN + i] : 0.f;
        }
      } else if (tid >= 96 && tid < 103) {
        if (t + 1 < T_) {
          int j = tid - 96;
          const float* xp = xb + (size_t)(t + 1) * DIN;
          float a0 = xp[2 * j];
          float a1 = (j == 6) ? 0.f : xp[2 * j + 1];
          ((uint32_t*)sm.zg)[j] = pk2(a0, a1);
        }
      }
      __syncthreads();
    }
  } else {
    // ======================= role B =======================
    SMB& sm = *(SMB*)smraw;
    for (int i = tid; i < Q2N * RB; i += 512) {
      int q = i / RB, r = i % RB, mat = r / UB, u = r % UB;
      sm.l2w[i] = P.wsL2[q * NR2 + mat * 128 + UA + u];
    }
    for (int i = tid; i < RB; i += 512) sm.cb2[i] = P.b2[i / UB][UA + i % UB];
    for (int i = tid; i < 12 * 128; i += 512) {
      int r = i >> 7, k = i & 127;
      sm.hw[r][k] = (r < 3) ? P.gW[r * 128 + k]
                  : (r < 6) ? P.aW[(r - 3) * 128 + k]
                            : P.uW[(r - 6) * 128 + k];
    }
    if (tid < 12) sm.hb[tid] = (tid < 3) ? P.gb[tid] : (tid < 6) ? P.ab[tid - 3] : P.ub[tid - 6];
    {
      uint32_t* z = (uint32_t*)sm.zg;
      for (int i = tid; i < (QG + Q2N) * 4; i += 512) z[i] = 0u;
    }
    if (tid < 16) sm.xt[tid] = (tid < DIN) ? xb[tid] : 0.f;
    const int grow = ((tid >> 7) << 8) + 128 + (tid & 127);   // units 128..255
    const float bg = P.bih[grow] + P.bhh[grow];
    float c_r = 0.f;
    __syncthreads();
    if (tid < 7) {
      float a0 = xb[2 * tid];
      float a1 = (tid == 6) ? 0.f : xb[2 * tid + 1];
      ((uint32_t*)sm.zg)[tid] = pk2(a0, a1);
    }
    __syncthreads();

    for (int t = 0; t < T_; ++t) {
      // Q1: gates
      {
        float acc = bg;
#pragma unroll 8
        for (int q = 0; q < QG; ++q)
          acc = dot8f(P.wsG[q * NRG + grow], sm.zg[q], acc);
        sm.garr[tid] = acc;
      }
      __syncthreads();
      // Q2: LSTM units 128..255
      if (tid < 128) {
        float gi = sm.garr[tid], gf = sm.garr[128 + tid];
        float gg = sm.garr[256 + tid], go = sm.garr[384 + tid];
        float cn = sigf(gf) * c_r + sigf(gi) * tanhf(gg);
        c_r = cn;
        sm.hB[tid] = sigf(go) * tanhf(cn);
      }
      __syncthreads();
      // Q3: S1 store + z2 hi words 28..91 (pure h region)
      if (tid < 128) {
        S1[tid] = sm.hB[tid];
      } else if (tid < 192) {
        int j = 28 + (tid - 128);
        int k = 2 * j;
        float a0 = (k < KL2) ? sm.hB[k - N1] : 0.f;
        float a1 = (k + 1 < KL2) ? sm.hB[k + 1 - N1] : 0.f;
        ((uint32_t*)sm.z2)[j] = pk2(a0, a1);
      }
      __syncthreads();
      if (tid == 0)
        __hip_atomic_store(f1, t + 1, __ATOMIC_RELEASE, __HIP_MEMORY_SCOPE_AGENT);
      // Q4: l2B part1 (quads 7..22, h-region) — overlaps A's l0/l1
      float a0 = 0.f, a1 = 0.f, a2 = 0.f, a3 = 0.f;
      if (tid < UB) {
        a0 = sm.cb2[tid]; a1 = sm.cb2[UB + tid];
        a2 = sm.cb2[2 * UB + tid]; a3 = sm.cb2[3 * UB + tid];
#pragma unroll
        for (int q = 7; q < Q2N; ++q) {
          uint4 z = sm.z2[q];
          a0 = dot8f(sm.l2w[q * RB + tid], z, a0);
          a1 = dot8f(sm.l2w[q * RB + UB + tid], z, a1);
          a2 = dot8f(sm.l2w[q * RB + 2 * UB + tid], z, a2);
          a3 = dot8f(sm.l2w[q * RB + 3 * UB + tid], z, a3);
        }
      }
      // Q5: wait f2
      if (tid == 0) {
        while (__hip_atomic_load(f2, __ATOMIC_RELAXED, __HIP_MEMORY_SCOPE_AGENT) < t + 1)
          __builtin_amdgcn_s_sleep(1);
        (void)__hip_atomic_load(f2, __ATOMIC_ACQUIRE, __HIP_MEMORY_SCOPE_AGENT);
      }
      __syncthreads();
      // Q6: z2 lo words 0..27 + zg h-words 0..63 (direct from S2 global)
      if (tid < 28) {
        int k = 2 * tid;
        float a0z = (k < N1) ? S2[N0 + k] : sm.hB[k - N1];
        float a1z = (k + 1 < N1) ? S2[N0 + k + 1] : sm.hB[k + 1 - N1];
        ((uint32_t*)sm.z2)[tid] = pk2(a0z, a1z);
      } else if (tid >= 64 && tid < 128) {
        int j = tid - 64;
        ((uint32_t*)sm.zg)[7 + j] = pk2(S2[2 * j], S2[2 * j + 1]);
      }
      __syncthreads();
      // Q7: l2B part2 (quads 0..6) + combine + S3b
      if (tid < UB) {
#pragma unroll
        for (int q = 0; q < 7; ++q) {
          uint4 z = sm.z2[q];
          a0 = dot8f(sm.l2w[q * RB + tid], z, a0);
          a1 = dot8f(sm.l2w[q * RB + UB + tid], z, a1);
          a2 = dot8f(sm.l2w[q * RB + 2 * UB + tid], z, a2);
          a3 = dot8f(sm.l2w[q * RB + 3 * UB + tid], z, a3);
        }
        float ti = sigf(a2 + a3);
        float v = tanhf(a0) * (1.f - ti) + ti * tanhf(a1);
        sm.motor[UA + tid] = v;
        S3b[tid] = v;
      }
      __syncthreads();
      // Q8: release f3b, wait f3a
      if (tid == 0) {
        __hip_atomic_store(f3b, t + 1, __ATOMIC_RELEASE, __HIP_MEMORY_SCOPE_AGENT);
        while (__hip_atomic_load(f3a, __ATOMIC_RELAXED, __HIP_MEMORY_SCOPE_AGENT) < t + 1)
          __builtin_amdgcn_s_sleep(1);
        (void)__hip_atomic_load(f3a, __ATOMIC_ACQUIRE, __HIP_MEMORY_SCOPE_AGENT);
      }
      __syncthreads();
      // Q9: tail — motor lo, zg h-words 64..127, next x
      if (tid < UA) {
        sm.motor[tid] = S3a[tid];
      } else if (tid >= 32 && tid < 46) {
        int i = tid - 32;
        ((uint32_t*)sm.zg)[7 + 64 + i] = pk2(S3a[2 * i], S3a[2 * i + 1]);
      } else if (tid >= 64 && tid < 114) {
        int j = 78 + (tid - 64);
        ((uint32_t*)sm.zg)[7 + j] = pk2(sm.motor[2 * j - 128], sm.motor[2 * j - 127]);
      } else if (tid >= 120 && tid < 136) {
        if (t + 1 < T_) {
          int i = tid - 120;
          sm.xt[i] = (i < DIN) ? xb[(size_t)(t + 1) * DIN + i] : 0.f;
        }
      } else if (tid >= 144 && tid < 151) {
        if (t + 1 < T_) {
          int j = tid - 144;
          const float* xp = xb + (size_t)(t + 1) * DIN;
          float a0x = xp[2 * j];
          float a1x = (j == 6) ? 0.f : xp[2 * j + 1];
          ((uint32_t*)sm.zg)[j] = pk2(a0x, a1x);
        }
      }
      __syncthreads();
      // Q10: heads partials (48 threads)
      if (tid < 48) {
        int r = tid >> 2, s = tid & 3;
        const float* m = sm.motor + 32 * s;
        const float* w = sm.hw[r] + 32 * s;
        float p0 = 0.f, p1 = 0.f;
#pragma unroll
        for (int k = 0; k < 32; k += 2) { p0 += w[k] * m[k]; p1 += w[k + 1] * m[k + 1]; }
        sm.part[r][s] = p0 + p1;
      }
      __syncthreads();
      // Q11: heads final + store
      if (tid < 12) {
        float a = sm.hb[tid] + sm.part[tid][0] + sm.part[tid][1] + sm.part[tid][2] + sm.part[tid][3];
        size_t base = ((size_t)b * T_ + t) * 6;
        if (tid < 6) P.out[base + tid] = a;
        else {
          float sp = (a > 0.f) ? (a + log1pf(expf(-a))) : log1pf(expf(a));
          P.out[UNC_OFF + base + (tid - 6)] = sp;
        }
      }
      // no barrier needed: next gates touch only zg/garr, not part/out
    }
  }
}

// ================= round-1 single-WG kernel (fallback path) =================

struct SM {
  uint4 zg[QG];
  uint4 z0[Q0];
  uint4 z1[Q1];
  uint4 z2[Q2];
  uint4 ld0[Q0 * NR0];
  uint4 ld1[Q1 * NR1];
  float xt[16];
  float lstm_h[HS];
  float hprev[HS];
  float garr[4 * HS];
  float ffb[4][128];
  float cb0[NR0];
  float cb1[NR1];
  float cb2[NR2];
  float hw[12][132];
  float hb[12];
};

struct Args {
  const float* x;
  const float* Wih; const float* Whh; const float* bih; const float* bhh;
  const float* W0[4]; const float* b0[4]; const float* m0;
  const float* W1[4]; const float* b1[4]; const float* m1;
  const float* W2[4]; const float* b2[4]; const float* m2;
  const float* gW; const float* gb; const float* aW; const float* ab;
  const float* uW; const float* ub;
  const uint4* wsG; const uint4* wsL0; const uint4* wsL1; const uint4* wsL2;
  float* out;
};

template <bool PK>
__global__ __launch_bounds__(512, 1) void rnn_persist(Args A) {
  extern __shared__ char smraw[];
  SM& sm = *(SM*)smraw;
  const int tid = threadIdx.x;
  const int b = blockIdx.x;

  for (int i = tid; i < NR0; i += 512) sm.cb0[i] = A.b0[i / N0][i % N0];
  for (int i = tid; i < NR1; i += 512) sm.cb1[i] = A.b1[i / N1][i % N1];
  for (int i = tid; i < NR2; i += 512) sm.cb2[i] = A.b2[i / N2][i % N2];
  for (int i = tid; i < 12 * 128; i += 512) {
    int r = i >> 7, k = i & 127;
    sm.hw[r][k] = (r < 3) ? A.gW[r * 128 + k]
                : (r < 6) ? A.aW[(r - 3) * 128 + k]
                          : A.uW[(r - 6) * 128 + k];
  }
  if (tid < 12) sm.hb[tid] = (tid < 3) ? A.gb[tid] : (tid < 6) ? A.ab[tid - 3] : A.ub[tid - 6];
  for (int i = tid; i < HS; i += 512) sm.hprev[i] = 0.f;
  {
    uint32_t* zz = (uint32_t*)sm.zg;
    for (int i = tid; i < (QG + Q0 + Q1 + Q2) * 4; i += 512) zz[i] = 0u;
  }
  if (PK) {
    for (int i = tid; i < Q0 * NR0; i += 512) sm.ld0[i] = A.wsL0[i];
    for (int i = tid; i < Q1 * NR1; i += 512) sm.ld1[i] = A.wsL1[i];
  }
  float bga = A.bih[tid] + A.bhh[tid];
  float bgb = A.bih[tid + 512] + A.bhh[tid + 512];
  float c_r = 0.f;
  __syncthreads();

  uint32_t* zgu = (uint32_t*)sm.zg;
  uint32_t* z0u = (uint32_t*)sm.z0;
  uint32_t* z1u = (uint32_t*)sm.z1;
  uint32_t* z2u = (uint32_t*)sm.z2;

  const float* xb = A.x + (size_t)b * T_ * DIN;
  float* outP = A.out;
  const size_t UNC_OFF = (size_t)B_ * T_ * 6;

  for (int t = 0; t < T_; ++t) {
    const float* xp = xb + (size_t)t * DIN;
    if (tid < DIN) sm.xt[tid] = xp[tid];
    if (PK && tid < 7) {
      float a0 = xp[2 * tid];
      float a1 = (tid == 6) ? 0.f : xp[2 * tid + 1];
      zgu[tid] = pk2(a0, a1);
    }
    __syncthreads();

    float aa = bga, ab = bgb;
    if (PK) {
#pragma unroll 4
      for (int q = 0; q < QG; ++q) {
        uint4 z = sm.zg[q];
        uint4 wa = A.wsG[q * NRG + tid];
        uint4 wb = A.wsG[q * NRG + 512 + tid];
        aa = dot8f(wa, z, aa);
        ab = dot8f(wb, z, ab);
      }
    } else {
      for (int k = 0; k < DIN; ++k) {
        float xv = sm.xt[k];
        aa += A.Wih[tid * DIN + k] * xv;
        ab += A.Wih[(tid + 512) * DIN + k] * xv;
      }
      for (int k = 0; k < HS; ++k) {
        float hv = sm.hprev[k];
        aa += A.Whh[tid * HS + k] * hv;
        ab += A.Whh[(tid + 512) * HS + k] * hv;
      }
    }
    sm.garr[tid] = aa;
    sm.garr[tid + 512] = ab;
    __syncthreads();

    if (tid < HS) {
      float gi = sm.garr[tid], gf = sm.garr[HS + tid];
      float gg = sm.garr[2 * HS + tid], go = sm.garr[3 * HS + tid];
      float cn = sigf(gf) * c_r + sigf(gi) * tanhf(gg);
      c_r = cn;
      sm.lstm_h[tid] = sigf(go) * tanhf(cn);
    }
    __syncthreads();

    if (PK && tid < 45) {
      int k = 2 * tid;
      float s0 = (k < DIN) ? sm.xt[k] : sm.lstm_h[k - DIN];
      ++k;
      float s1 = (k < DIN) ? sm.xt[k] : sm.lstm_h[k - DIN];
      z0u[tid] = pk2(s0, s1);
    }
    __syncthreads();

    if (tid < NR0) {
      int mat = tid / N0, o = tid % N0;
      float acc = sm.cb0[tid];
      if (PK) {
#pragma unroll
        for (int q = 0; q < Q0; ++q) acc = dot8f(sm.ld0[q * NR0 + tid], sm.z0[q], acc);
      } else {
        const float* W = A.W0[mat];
        const float* m = A.m0;
        const int Kl = DIN + N0;
        for (int k = 0; k < DIN; ++k) {
          float w = W[o * Kl + k];
          if (mat < 2) w *= m[o * Kl + k];
          acc += w * sm.xt[k];
        }
        for (int k = DIN; k < Kl; ++k) acc += W[o * Kl + k] * sm.lstm_h[k - DIN];
      }
      sm.ffb[mat][o] = (mat < 2) ? tanhf(acc) : acc;
    }
    __syncthreads();
    if (tid < N0) {
      float ti = sigf(sm.ffb[2][tid] + sm.ffb[3][tid]);
      sm.hprev[tid] = sm.ffb[0][tid] * (1.f - ti) + ti * sm.ffb[1][tid];
    }
    __syncthreads();

    if (PK && tid < Q1 * 4) {
      int k = 2 * tid;
      float s0 = (k < N0) ? sm.hprev[k] : sm.lstm_h[k];
      ++k;
      float s1 = (k < N0) ? sm.hprev[k] : sm.lstm_h[k];
      z1u[tid] = pk2(s0, s1);
    }
    __syncthreads();

    if (tid < NR1) {
      int mat = tid / N1, o = tid % N1;
      float acc = sm.cb1[tid];
      if (PK) {
#pragma unroll
        for (int q = 0; q < Q1; ++q) acc = dot8f(sm.ld1[q * NR1 + tid], sm.z1[q], acc);
      } else {
        const float* W = A.W1[mat];
        const float* m = A.m1;
        const int Kl = N0 + N1;
        for (int k = 0; k < N0; ++k) {
          float w = W[o * Kl + k];
          if (mat < 2) w *= m[o * Kl + k];
          acc += w * sm.hprev[k];
        }
        for (int k = N0; k < Kl; ++k) acc += W[o * Kl + k] * sm.lstm_h[k];
      }
      sm.ffb[mat][o] = (mat < 2) ? tanhf(acc) : acc;
    }
    __syncthreads();
    if (tid < N1) {
      float ti = sigf(sm.ffb[2][tid] + sm.ffb[3][tid]);
      sm.hprev[N0 + tid] = sm.ffb[0][tid] * (1.f - ti) + ti * sm.ffb[1][tid];
    }
    __syncthreads();

    if (PK && tid < 90) {
      int k = 2 * tid;
      float s0 = (k < N1) ? sm.hprev[N0 + k] : sm.lstm_h[N0 + k];
      ++k;
      float s1 = (k >= KL2) ? 0.f : ((k < N1) ? sm.hprev[N0 + k] : sm.lstm_h[N0 + k]);
      z2u[tid] = pk2(s0, s1);
    }
    __syncthreads();

    {
      int mat = tid >> 7, o = tid & 127;
      float acc = sm.cb2[tid];
      if (PK) {
#pragma unroll 4
        for (int q = 0; q < Q2; ++q) acc = dot8f(A.wsL2[q * NR2 + tid], sm.z2[q], acc);
      } else {
        const float* W = A.W2[mat];
        const float* m = A.m2;
        const int Kl = N1 + N2;
        for (int k = 0; k < N1; ++k) {
          float w = W[o * Kl + k];
          if (mat < 2) w *= m[o * Kl + k];
          acc += w * sm.hprev[N0 + k];
        }
        for (int k = N1; k < Kl; ++k) acc += W[o * Kl + k] * sm.lstm_h[N0 + k];
      }
      sm.ffb[mat][o] = (mat < 2) ? tanhf(acc) : acc;
    }
    __syncthreads();
    if (tid < N2) {
      float ti = sigf(sm.ffb[2][tid] + sm.ffb[3][tid]);
      sm.hprev[N0 + N1 + tid] = sm.ffb[0][tid] * (1.f - ti) + ti * sm.ffb[1][tid];
    }
    __syncthreads();

    if (tid >= 256 && tid < 268) {
      int r = tid - 256;
      const float* mo = &sm.hprev[N0 + N1];
      float acc = sm.hb[r];
      for (int k = 0; k < 128; ++k) acc += sm.hw[r][k] * mo[k];
      size_t base = ((size_t)b * T_ + t) * 6;
      if (r < 6) {
        outP[base + r] = acc;
      } else {
        float sp = (acc > 0.f) ? (acc + log1pf(expf(-acc))) : log1pf(expf(acc));
        outP[UNC_OFF + base + (r - 6)] = sp;
      }
    }
    if (PK && tid < 128) {
      zgu[7 + tid] = pk2(sm.hprev[2 * tid], sm.hprev[2 * tid + 1]);
    }
    __syncthreads();
  }
}

// ---------------- launcher ----------------

extern "C" void kernel_launch(void* const* d_in, const int* in_sizes, int n_in,
                              void* d_out, int out_size, void* d_ws, size_t ws_size,
                              hipStream_t stream) {
  const float* x   = (const float*)d_in[0];
  const float* Wih = (const float*)d_in[1];
  const float* Whh = (const float*)d_in[2];
  const float* bih = (const float*)d_in[3];
  const float* bhh = (const float*)d_in[4];
  const float *W[3][4], *bb[3][4], *mk[3];
  for (int l = 0; l < 3; ++l) {
    int base = 5 + l * 9;
    for (int nm = 0; nm < 4; ++nm) {
      W[l][nm]  = (const float*)d_in[base + 2 * nm];
      bb[l][nm] = (const float*)d_in[base + 2 * nm + 1];
    }
    mk[l] = (const float*)d_in[base + 8];
  }
  const float* gW = (const float*)d_in[32];
  const float* gb = (const float*)d_in[33];
  const float* aW = (const float*)d_in[34];
  const float* ab = (const float*)d_in[35];
  const float* uW = (const float*)d_in[36];
  const float* ub = (const float*)d_in[37];

  char* ws = (char*)d_ws;
  const size_t szG   = (size_t)QG * NRG * 16;     // 557056
  const size_t szL0  = (size_t)Q0 * NR0 * 16;     // 59136
  const size_t szL1  = (size_t)Q1 * NR1 * 16;     // 52224
  const size_t szL2N = (size_t)Q2N * NR2 * 16;    // 188416
  const size_t offG = 0, offL0 = szG, offL1 = offL0 + szL0, offL2 = offL1 + szL1;
  const size_t offSync = offL2 + szL2N;           // 856832
  const size_t syncBytes = 128 * 128 * 4 * 3 + 128 * 32 * 4 * 2;  // S1,S2,S3b + S3a,flags = 229376
  const size_t need_new = offSync + syncBytes;    // 1086208

  const size_t szL2O = (size_t)Q2 * NR2 * 16;     // 196608 (old layout)
  const size_t need_old = offL2 + szL2O;          // 865024

  if (ws_size >= need_new) {
    PArgs P;
    P.x = x; P.bih = bih; P.bhh = bhh;
    for (int nm = 0; nm < 4; ++nm) { P.b0[nm] = bb[0][nm]; P.b1[nm] = bb[1][nm]; P.b2[nm] = bb[2][nm]; }
    P.gW = gW; P.gb = gb; P.aW = aW; P.ab = ab; P.uW = uW; P.ub = ub;
    P.wsG  = (const uint4*)(ws + offG);
    P.wsL0 = (const uint4*)(ws + offL0);
    P.wsL1 = (const uint4*)(ws + offL1);
    P.wsL2 = (const uint4*)(ws + offL2);
    char* sy = ws + offSync;
    P.S1  = (float*)(sy);
    P.S2  = (float*)(sy + 65536);
    P.S3b = (float*)(sy + 131072);
    P.S3a = (float*)(sy + 196608);
    P.flags = (int*)(sy + 212992);
    P.out = (float*)d_out;

    hipMemsetAsync(sy, 0, syncBytes, stream);
    int n;
    n = K2G * NRG;
    prep_gates<<<(n + 255) / 256, 256, 0, stream>>>(Wih, Whh, (uint32_t*)(ws + offG));
    n = NR0 * K2_0;
    prep_cfc<<<(n + 255) / 256, 256, 0, stream>>>(W[0][0], W[0][1], W[0][2], W[0][3], mk[0],
                                                  N0, DIN, NR0, K2_0, (uint32_t*)(ws + offL0));
    n = NR1 * K2_1;
    prep_cfc<<<(n + 255) / 256, 256, 0, stream>>>(W[1][0], W[1][1], W[1][2], W[1][3], mk[1],
                                                  N1, N0, NR1, K2_1, (uint32_t*)(ws + offL1));
    n = NR2 * K2N;
    prep_cfc<<<(n + 255) / 256, 256, 0, stream>>>(W[2][0], W[2][1], W[2][2], W[2][3], mk[2],
                                                  N2, N1, NR2, K2N, (uint32_t*)(ws + offL2));
    int lds = (int)((sizeof(SMA) > sizeof(SMB)) ? sizeof(SMA) : sizeof(SMB));
    hipFuncSetAttribute(reinterpret_cast<const void*>(&rnn_pair),
                        hipFuncAttributeMaxDynamicSharedMemorySize, lds);
    rnn_pair<<<2 * B_, 512, lds, stream>>>(P);
    return;
  }

  // -------- fallback: round-1 single-WG design --------
  Args A;
  A.x = x; A.Wih = Wih; A.Whh = Whh; A.bih = bih; A.bhh = bhh;
  for (int nm = 0; nm < 4; ++nm) {
    A.W0[nm] = W[0][nm]; A.b0[nm] = bb[0][nm];
    A.W1[nm] = W[1][nm]; A.b1[nm] = bb[1][nm];
    A.W2[nm] = W[2][nm]; A.b2[nm] = bb[2][nm];
  }
  A.m0 = mk[0]; A.m1 = mk[1]; A.m2 = mk[2];
  A.gW = gW; A.gb = gb; A.aW = aW; A.ab = ab; A.uW = uW; A.ub = ub;
  A.out = (float*)d_out;
  A.wsG  = (const uint4*)(ws + offG);
  A.wsL0 = (const uint4*)(ws + offL0);
  A.wsL1 = (const uint4*)(ws + offL1);
  A.wsL2 = (const uint4*)(ws + offL2);

  const bool pk = (ws_size >= need_old);
  if (pk) {
    int n;
    n = K2G * NRG;
    prep_gates<<<(n + 255) / 256, 256, 0, stream>>>(Wih, Whh, (uint32_t*)(ws + offG));
    n = NR0 * K2_0;
    prep_cfc<<<(n + 255) / 256, 256, 0, stream>>>(W[0][0], W[0][1], W[0][2], W[0][3], mk[0],
                                                  N0, DIN, NR0, K2_0, (uint32_t*)(ws + offL0));
    n = NR1 * K2_1;
    prep_cfc<<<(n + 255) / 256, 256, 0, stream>>>(W[1][0], W[1][1], W[1][2], W[1][3], mk[1],
                                                  N1, N0, NR1, K2_1, (uint32_t*)(ws + offL1));
    n = NR2 * K2_2;
    prep_cfc<<<(n + 255) / 256, 256, 0, stream>>>(W[2][0], W[2][1], W[2][2], W[2][3], mk[2],
                                                  N2, N1, NR2, K2_2, (uint32_t*)(ws + offL2));
    hipFuncSetAttribute(reinterpret_cast<const void*>(&rnn_persist<true>),
                        hipFuncAttributeMaxDynamicSharedMemorySize, (int)sizeof(SM));
    rnn_persist<true><<<B_, 512, sizeof(SM), stream>>>(A);
  } else {
    hipFuncSetAttribute(reinterpret_cast<const void*>(&rnn_persist<false>),
                        hipFuncAttributeMaxDynamicSharedMemorySize, (int)sizeof(SM));
    rnn_persist<false><<<B_, 512, sizeof(SM), stream>>>(A);
  }
}